// Round 1
// baseline (2947.342 us; speedup 1.0000x reference)
//
#include <hip/hip_runtime.h>

// Problem constants (fixed by the reference)
#define BB    8
#define NN    8192
#define MM    2048
#define CFEAT 64
#define OUTC  128
#define NS    32

// ---------------------------------------------------------------------------
// K1: Farthest point sampling on scale_xyz = xyz + key_mask*(n+10)*10.
// One block per batch, 512 threads, 16 points/thread held in registers.
// Per iteration: distance update (direct form, matches reference rounding
// up to FMA contraction), block max via wave butterfly + LDS, lowest-index
// tie-break via LDS atomicMin, winner coords broadcast via owner-write LDS.
// ---------------------------------------------------------------------------
#define FPS_T  512
#define FPS_PT (NN / FPS_T)   // 16

__global__ __launch_bounds__(FPS_T) void fps_kernel(
    const float* __restrict__ xyz, const int* __restrict__ key_mask,
    int* __restrict__ fps_idx)
{
    const int b    = blockIdx.x;
    const int t    = threadIdx.x;
    const int lane = t & 63;
    const int w    = t >> 6;

    __shared__ float s_wmax[FPS_T / 64];
    __shared__ int   s_win[2];
    __shared__ float s_qc[3];

    float px[FPS_PT], py[FPS_PT], pz[FPS_PT], dmin[FPS_PT];
    #pragma unroll
    for (int j = 0; j < FPS_PT; ++j) {
        int idx = t + j * FPS_T;
        const float* p = xyz + ((size_t)b * NN + idx) * 3;
        float km  = (float)key_mask[b * NN + idx];
        float sc  = ((float)idx + 10.0f) * 10.0f;
        float off = km * sc;                // exact: km in {0,1}, sc exact int
        px[j] = p[0] + off;
        py[j] = p[1] + off;
        pz[j] = p[2] + off;
        dmin[j] = 1e10f;
    }
    if (t == 0) {
        s_win[0] = 0x7fffffff; s_win[1] = 0x7fffffff;
        s_qc[0] = px[0]; s_qc[1] = py[0]; s_qc[2] = pz[0];   // point 0
    }
    __syncthreads();

    int last = 0;
    for (int it = 0; it < MM; ++it) {
        if (t == 0) fps_idx[b * MM + it] = last;
        const float qx = s_qc[0], qy = s_qc[1], qz = s_qc[2];

        // distance update + thread-local max (4 parallel chains for ILP)
        float tm[4] = {-1.f, -1.f, -1.f, -1.f};
        #pragma unroll
        for (int j = 0; j < FPS_PT; ++j) {
            float dx = px[j] - qx;
            float dy = py[j] - qy;
            float dz = pz[j] - qz;
            float d  = dx * dx + dy * dy + dz * dz;   // ((dx^2+dy^2)+dz^2)
            float dm = fminf(dmin[j], d);
            dmin[j]  = dm;
            tm[j & 3] = fmaxf(tm[j & 3], dm);
        }
        float tloc = fmaxf(fmaxf(tm[0], tm[1]), fmaxf(tm[2], tm[3]));

        // wave butterfly max
        float wm = tloc;
        #pragma unroll
        for (int s = 1; s < 64; s <<= 1) wm = fmaxf(wm, __shfl_xor(wm, s));
        if (lane == 0) s_wmax[w] = wm;
        __syncthreads();                                   // b1

        float bmax = s_wmax[0];
        #pragma unroll
        for (int k = 1; k < FPS_T / 64; ++k) bmax = fmaxf(bmax, s_wmax[k]);

        if (t == 0) s_win[(it + 1) & 1] = 0x7fffffff;      // reset other slot

        if (tloc == bmax) {   // rare: candidate thread(s) only
            int cand = 0x7fffffff;
            #pragma unroll
            for (int j = FPS_PT - 1; j >= 0; --j)          // descending -> lowest j wins
                if (dmin[j] == bmax) cand = t + j * FPS_T;
            atomicMin(&s_win[it & 1], cand);               // lowest global index
        }
        __syncthreads();                                   // b2
        last = s_win[it & 1];

        // owner thread publishes winner coords for next iteration
        if (t == (last & (FPS_T - 1))) {
            int jj = last >> 9;                            // log2(FPS_T)
            float ox = 0.f, oy = 0.f, oz = 0.f;
            #pragma unroll
            for (int j = 0; j < FPS_PT; ++j)
                if (jj == j) { ox = px[j]; oy = py[j]; oz = pz[j]; }
            s_qc[0] = ox; s_qc[1] = oy; s_qc[2] = oz;
        }
        __syncthreads();                                   // b3
    }
}

// ---------------------------------------------------------------------------
// K2: G[p][o] = sum_c feat[p][c] * W[o][c]  for c in [0,64), all 65536 points.
// W staged transposed in LDS; feat value broadcast across the wave via shfl.
// ---------------------------------------------------------------------------
__global__ __launch_bounds__(256) void featW_kernel(
    const float* __restrict__ feat, const float* __restrict__ W,
    float* __restrict__ G)
{
    __shared__ float Wt[CFEAT * OUTC];   // [c][o], 32 KB
    const int t = threadIdx.x;
    for (int i = t; i < CFEAT * OUTC; i += 256) {
        int c = i >> 7, o = i & 127;
        Wt[i] = W[o * 67 + c];
    }
    __syncthreads();

    const int lane = t & 63, w = t >> 6;
    const int p0 = (blockIdx.x * 4 + w) * 16;
    for (int k = 0; k < 16; ++k) {
        int p = p0 + k;
        float fv = feat[(size_t)p * CFEAT + lane];
        float a0 = 0.f, a1 = 0.f;
        #pragma unroll
        for (int c = 0; c < CFEAT; ++c) {
            float fc = __shfl(fv, c);
            a0 = fmaf(fc, Wt[c * OUTC + lane], a0);
            a1 = fmaf(fc, Wt[c * OUTC + 64 + lane], a1);
        }
        G[(size_t)p * OUTC + lane]      = a0;
        G[(size_t)p * OUTC + 64 + lane] = a1;
    }
}

// ---------------------------------------------------------------------------
// K3: fused ball query + gather + (G + gxyz*Wxyz + b) + LeakyReLU + pool.
// One wave per query; neighbor indices staged in per-wave LDS.
// d2 uses the reference's expanded form q2 + p2 - 2*dot.
// ---------------------------------------------------------------------------
__global__ __launch_bounds__(256) void group_kernel(
    const float* __restrict__ xyz, const int* __restrict__ mask,
    const int* __restrict__ key_mask, const float* __restrict__ W,
    const float* __restrict__ bias, const int* __restrict__ fps_idx,
    const float* __restrict__ G, float* __restrict__ out)
{
    __shared__ int s_idx[4][NS];
    const int t = threadIdx.x, lane = t & 63, w = t >> 6;
    const int q = blockIdx.x * 4 + w;         // 0..16383
    const int b = q >> 11;
    const int gi = fps_idx[q];

    const float* xb = xyz + (size_t)b * NN * 3;
    const float* qp = xb + (size_t)gi * 3;
    const float qx = qp[0], qy = qp[1], qz = qp[2];

    float* out0 = out;
    float* onx  = out  + (size_t)BB * MM * OUTC;
    float* onm  = onx  + (size_t)BB * MM * 3;
    float* onk  = onm  + (size_t)BB * MM;
    if (lane == 0) {
        onx[(size_t)q * 3 + 0] = qx;
        onx[(size_t)q * 3 + 1] = qy;
        onx[(size_t)q * 3 + 2] = qz;
        onm[q] = (float)mask[b * NN + gi];
        onk[q] = (float)key_mask[b * NN + gi];
    }

    const float q2 = qx * qx + qy * qy + qz * qz;
    int have = 0, idx0 = -1;
    for (int base = 0; base < NN; base += 64) {
        int n = base + lane;
        const float* p = xb + n * 3;
        float x = p[0], y = p[1], z = p[2];
        float p2 = x * x + y * y + z * z;
        float dt = qx * x + qy * y + qz * z;
        float d2 = (q2 + p2) - 2.0f * dt;
        bool within = d2 < 0.25f;
        unsigned long long bm = __ballot(within);
        if (bm) {
            if (idx0 < 0) idx0 = base + (__ffsll(bm) - 1);
            if (within) {
                int pos = have + __popcll(bm & ((1ull << lane) - 1ull));
                if (pos < NS) s_idx[w][pos] = n;
            }
            have += (int)__popcll(bm);
            if (have >= NS) break;
        }
    }
    if (have > NS) have = NS;
    if (lane >= have && lane < NS) s_idx[w][lane] = idx0;   // pad with first valid
    __asm__ volatile("s_waitcnt lgkmcnt(0)" ::: "memory");  // LDS writes visible to wave

    // per-lane xyz weights + bias: lane -> channels (lane) and (lane+64)
    const float w0x = W[lane * 67 + 64], w0y = W[lane * 67 + 65], w0z = W[lane * 67 + 66];
    const float w1x = W[(lane + 64) * 67 + 64], w1y = W[(lane + 64) * 67 + 65], w1z = W[(lane + 64) * 67 + 66];
    const float b0 = bias[lane], b1 = bias[lane + 64];
    const float* Gb = G + (size_t)b * NN * OUTC;

    float acc = 0.f, mx = -3.4e38f;
    #pragma unroll 4
    for (int s = 0; s < NS; ++s) {
        int id = s_idx[w][s];
        const float* pr = xb + (size_t)id * 3;
        float dx = pr[0] - qx, dy = pr[1] - qy, dz = pr[2] - qz;
        const float* g = Gb + (size_t)id * OUTC;
        float y0 = g[lane]      + dx * w0x + dy * w0y + dz * w0z + b0;
        float y1 = g[lane + 64] + dx * w1x + dy * w1y + dz * w1z + b1;
        y0 = y0 > 0.f ? y0 : 0.01f * y0;
        y1 = y1 > 0.f ? y1 : 0.01f * y1;
        acc += y0;
        mx = fmaxf(mx, y1);
    }
    out0[(size_t)q * OUTC + lane]      = acc * (1.0f / 32.0f);
    out0[(size_t)q * OUTC + 64 + lane] = mx;
}

// ---------------------------------------------------------------------------
extern "C" void kernel_launch(void* const* d_in, const int* in_sizes, int n_in,
                              void* d_out, int out_size, void* d_ws, size_t ws_size,
                              hipStream_t stream)
{
    const float* feat  = (const float*)d_in[0];
    const float* xyz   = (const float*)d_in[1];
    const int*   mask  = (const int*)d_in[2];
    const int*   kmask = (const int*)d_in[3];
    const float* W     = (const float*)d_in[4];
    const float* bias  = (const float*)d_in[5];
    float* out = (float*)d_out;

    int*   fps_idx = (int*)d_ws;                          // 8*2048*4 = 64 KB
    float* G       = (float*)((char*)d_ws + 65536);       // 65536*128*4 = 32 MB

    hipLaunchKernelGGL(featW_kernel, dim3(1024), dim3(256), 0, stream, feat, W, G);
    hipLaunchKernelGGL(fps_kernel,   dim3(BB),   dim3(FPS_T), 0, stream, xyz, kmask, fps_idx);
    hipLaunchKernelGGL(group_kernel, dim3(4096), dim3(256), 0, stream,
                       xyz, mask, kmask, W, bias, fps_idx, G, out);
}

// Round 2
// 2730.302 us; speedup vs baseline: 1.0795x; 1.0795x over previous
//
#include <hip/hip_runtime.h>

// Problem constants (fixed by the reference)
#define BB    8
#define NN    8192
#define MM    2048
#define CFEAT 64
#define OUTC  128
#define NS    32

// ---------------------------------------------------------------------------
// K1: Farthest point sampling on scale_xyz = xyz + key_mask*(n+10)*10.
// One block per batch, 512 threads, 16 points/thread in registers.
// Single barrier per iteration:
//   - incremental (dist,idx) argmax per thread during the distance update
//   - u64 packed (dist_bits<<32)|(NN-1-idx) wave butterfly (ties -> lowest idx)
//   - lane0 -> LDS, one __syncthreads, all threads reduce the 8 wave results
//   - winner coords fetched as one uniform float4 load from global scratch
// ---------------------------------------------------------------------------
#define FPS_T  512
#define FPS_PT (NN / FPS_T)   // 16

__global__ __launch_bounds__(FPS_T) void fps_kernel(
    const float* __restrict__ xyz, const int* __restrict__ key_mask,
    int* __restrict__ fps_idx, float4* sxyz)
{
    const int b    = blockIdx.x;
    const int t    = threadIdx.x;
    const int lane = t & 63;
    const int w    = t >> 6;

    __shared__ unsigned long long s_red[FPS_T / 64];

    float px[FPS_PT], py[FPS_PT], pz[FPS_PT], dmin[FPS_PT];
    #pragma unroll
    for (int j = 0; j < FPS_PT; ++j) {
        int idx = t + j * FPS_T;
        const float* p = xyz + ((size_t)b * NN + idx) * 3;
        float km  = (float)key_mask[b * NN + idx];
        float sc  = ((float)idx + 10.0f) * 10.0f;
        float off = km * sc;                // exact: km in {0,1}, sc exact int
        px[j] = p[0] + off;
        py[j] = p[1] + off;
        pz[j] = p[2] + off;
        dmin[j] = 1e10f;
        sxyz[(size_t)b * NN + idx] = make_float4(px[j], py[j], pz[j], 0.f);
    }
    __syncthreads();   // sxyz writes visible block-wide (same CU, L1 coherent)

    const float4* sb = sxyz + (size_t)b * NN;
    int last = 0;
    for (int it = 0; it < MM; ++it) {
        if (t == 0) fps_idx[b * MM + it] = last;
        const float4 qc = sb[last];        // uniform 16B load, L2-hot
        const float qx = qc.x, qy = qc.y, qz = qc.z;

        // distance update + incremental local argmax (ascending idx scan:
        // strict '>' keeps the lowest index among equal maxima)
        float m = -1.0f;
        int cidx = 0;
        #pragma unroll
        for (int j = 0; j < FPS_PT; ++j) {
            float dx = px[j] - qx;
            float dy = py[j] - qy;
            float dz = pz[j] - qz;
            float d  = dx * dx + dy * dy + dz * dz;
            float dm = fminf(dmin[j], d);
            dmin[j]  = dm;
            bool g   = dm > m;
            m    = g ? dm : m;
            cidx = g ? t + j * FPS_T : cidx;
        }

        // pack (dist, lowest-idx-wins) and butterfly across the wave
        unsigned long long pk =
            ((unsigned long long)__float_as_uint(m) << 32) |
            (unsigned int)(NN - 1 - cidx);
        #pragma unroll
        for (int s = 1; s < 64; s <<= 1) {
            unsigned long long o = __shfl_xor(pk, s);
            pk = o > pk ? o : pk;
        }
        if (lane == 0) s_red[w] = pk;
        __syncthreads();                                   // the only barrier

        // all threads reduce the 8 wave winners redundantly
        unsigned long long b0 = s_red[0] > s_red[1] ? s_red[0] : s_red[1];
        unsigned long long b1 = s_red[2] > s_red[3] ? s_red[2] : s_red[3];
        unsigned long long b2 = s_red[4] > s_red[5] ? s_red[4] : s_red[5];
        unsigned long long b3 = s_red[6] > s_red[7] ? s_red[6] : s_red[7];
        b0 = b0 > b1 ? b0 : b1;
        b2 = b2 > b3 ? b2 : b3;
        b0 = b0 > b2 ? b0 : b2;
        last = NN - 1 - (int)(unsigned int)b0;
    }
}

// ---------------------------------------------------------------------------
// K2: G[p][o] = sum_c feat[p][c] * W[o][c]  for c in [0,64), all 65536 points.
// ---------------------------------------------------------------------------
__global__ __launch_bounds__(256) void featW_kernel(
    const float* __restrict__ feat, const float* __restrict__ W,
    float* __restrict__ G)
{
    __shared__ float Wt[CFEAT * OUTC];   // [c][o], 32 KB
    const int t = threadIdx.x;
    for (int i = t; i < CFEAT * OUTC; i += 256) {
        int c = i >> 7, o = i & 127;
        Wt[i] = W[o * 67 + c];
    }
    __syncthreads();

    const int lane = t & 63, w = t >> 6;
    const int p0 = (blockIdx.x * 4 + w) * 16;
    for (int k = 0; k < 16; ++k) {
        int p = p0 + k;
        float fv = feat[(size_t)p * CFEAT + lane];
        float a0 = 0.f, a1 = 0.f;
        #pragma unroll
        for (int c = 0; c < CFEAT; ++c) {
            float fc = __shfl(fv, c);
            a0 = fmaf(fc, Wt[c * OUTC + lane], a0);
            a1 = fmaf(fc, Wt[c * OUTC + 64 + lane], a1);
        }
        G[(size_t)p * OUTC + lane]      = a0;
        G[(size_t)p * OUTC + 64 + lane] = a1;
    }
}

// ---------------------------------------------------------------------------
// K3: fused ball query + gather + (G + gxyz*Wxyz + b) + LeakyReLU + pool.
// ---------------------------------------------------------------------------
__global__ __launch_bounds__(256) void group_kernel(
    const float* __restrict__ xyz, const int* __restrict__ mask,
    const int* __restrict__ key_mask, const float* __restrict__ W,
    const float* __restrict__ bias, const int* __restrict__ fps_idx,
    const float* __restrict__ G, float* __restrict__ out)
{
    __shared__ int s_idx[4][NS];
    const int t = threadIdx.x, lane = t & 63, w = t >> 6;
    const int q = blockIdx.x * 4 + w;         // 0..16383
    const int b = q >> 11;
    const int gi = fps_idx[q];

    const float* xb = xyz + (size_t)b * NN * 3;
    const float* qp = xb + (size_t)gi * 3;
    const float qx = qp[0], qy = qp[1], qz = qp[2];

    float* out0 = out;
    float* onx  = out  + (size_t)BB * MM * OUTC;
    float* onm  = onx  + (size_t)BB * MM * 3;
    float* onk  = onm  + (size_t)BB * MM;
    if (lane == 0) {
        onx[(size_t)q * 3 + 0] = qx;
        onx[(size_t)q * 3 + 1] = qy;
        onx[(size_t)q * 3 + 2] = qz;
        onm[q] = (float)mask[b * NN + gi];
        onk[q] = (float)key_mask[b * NN + gi];
    }

    const float q2 = qx * qx + qy * qy + qz * qz;
    int have = 0, idx0 = -1;
    for (int base = 0; base < NN; base += 64) {
        int n = base + lane;
        const float* p = xb + n * 3;
        float x = p[0], y = p[1], z = p[2];
        float p2 = x * x + y * y + z * z;
        float dt = qx * x + qy * y + qz * z;
        float d2 = (q2 + p2) - 2.0f * dt;
        bool within = d2 < 0.25f;
        unsigned long long bm = __ballot(within);
        if (bm) {
            if (idx0 < 0) idx0 = base + (__ffsll(bm) - 1);
            if (within) {
                int pos = have + __popcll(bm & ((1ull << lane) - 1ull));
                if (pos < NS) s_idx[w][pos] = n;
            }
            have += (int)__popcll(bm);
            if (have >= NS) break;
        }
    }
    if (have > NS) have = NS;
    if (lane >= have && lane < NS) s_idx[w][lane] = idx0;   // pad with first valid
    __asm__ volatile("s_waitcnt lgkmcnt(0)" ::: "memory");  // LDS writes visible to wave

    const float w0x = W[lane * 67 + 64], w0y = W[lane * 67 + 65], w0z = W[lane * 67 + 66];
    const float w1x = W[(lane + 64) * 67 + 64], w1y = W[(lane + 64) * 67 + 65], w1z = W[(lane + 64) * 67 + 66];
    const float b0 = bias[lane], b1 = bias[lane + 64];
    const float* Gb = G + (size_t)b * NN * OUTC;

    float acc = 0.f, mx = -3.4e38f;
    #pragma unroll 4
    for (int s = 0; s < NS; ++s) {
        int id = s_idx[w][s];
        const float* pr = xb + (size_t)id * 3;
        float dx = pr[0] - qx, dy = pr[1] - qy, dz = pr[2] - qz;
        const float* g = Gb + (size_t)id * OUTC;
        float y0 = g[lane]      + dx * w0x + dy * w0y + dz * w0z + b0;
        float y1 = g[lane + 64] + dx * w1x + dy * w1y + dz * w1z + b1;
        y0 = y0 > 0.f ? y0 : 0.01f * y0;
        y1 = y1 > 0.f ? y1 : 0.01f * y1;
        acc += y0;
        mx = fmaxf(mx, y1);
    }
    out0[(size_t)q * OUTC + lane]      = acc * (1.0f / 32.0f);
    out0[(size_t)q * OUTC + 64 + lane] = mx;
}

// ---------------------------------------------------------------------------
extern "C" void kernel_launch(void* const* d_in, const int* in_sizes, int n_in,
                              void* d_out, int out_size, void* d_ws, size_t ws_size,
                              hipStream_t stream)
{
    const float* feat  = (const float*)d_in[0];
    const float* xyz   = (const float*)d_in[1];
    const int*   mask  = (const int*)d_in[2];
    const int*   kmask = (const int*)d_in[3];
    const float* W     = (const float*)d_in[4];
    const float* bias  = (const float*)d_in[5];
    float* out = (float*)d_out;

    int*    fps_idx = (int*)d_ws;                          // 64 KB
    float*  G       = (float*)((char*)d_ws + 65536);       // 32 MB
    float4* sxyz    = (float4*)((char*)d_ws + 65536 + (size_t)BB * NN * OUTC * 4); // 1 MB

    hipLaunchKernelGGL(featW_kernel, dim3(1024), dim3(256), 0, stream, feat, W, G);
    hipLaunchKernelGGL(fps_kernel,   dim3(BB),   dim3(FPS_T), 0, stream, xyz, kmask, fps_idx, sxyz);
    hipLaunchKernelGGL(group_kernel, dim3(4096), dim3(256), 0, stream,
                       xyz, mask, kmask, W, bias, fps_idx, G, out);
}

// Round 3
// 2529.169 us; speedup vs baseline: 1.1653x; 1.0795x over previous
//
#include <hip/hip_runtime.h>

// Problem constants (fixed by the reference)
#define BB    8
#define NN    8192
#define MM    2048
#define CFEAT 64
#define OUTC  128
#define NS    32

// ---------------------------------------------------------------------------
// Fused kernel: blocks 0..7 run FPS (one per batch); blocks 8.. run the
// feat*W precompute (G) concurrently on otherwise-idle CUs.
//
// FPS per iteration (2 barriers):
//   - dist update, 8 instr/pt, per-thread running max only (no idx tracking)
//   - f32 wave butterfly max -> lane0 -> LDS -> barrier
//   - all threads: 15-fmax tree over 16 partials (uniform float4 reads)
//   - threads with m==bmax (rare) scan their 8 dmin, atomicMin lowest global
//     index into LDS slot -> barrier -> everyone reads winner
//   - winner coords: uniform float4 load from precomputed scale_xyz scratch
// ---------------------------------------------------------------------------
#define FPS_T   1024
#define FPS_PT  (NN / FPS_T)    // 8
#define FPS_W   (FPS_T / 64)    // 16 waves
#define FW_BLOCKS 128
#define FW_PTS  ((BB * NN) / FW_BLOCKS)   // 512 points per featW block

__global__ __launch_bounds__(FPS_T) void fps_featw_kernel(
    const float* __restrict__ xyz, const int* __restrict__ key_mask,
    const float* __restrict__ feat, const float* __restrict__ W,
    int* __restrict__ fps_idx, float4* __restrict__ sxyz,
    float* __restrict__ G)
{
    __shared__ float smem[CFEAT * OUTC];   // 32 KB; featW: Wt[c][o]; FPS: header
    const int t    = threadIdx.x;
    const int lane = t & 63;
    const int w    = t >> 6;

    if (blockIdx.x >= BB) {
        // ---------------- featW path ----------------
        for (int i = t; i < CFEAT * OUTC; i += FPS_T) {
            int c = i >> 7, o = i & 127;
            smem[i] = W[o * 67 + c];
        }
        __syncthreads();
        const int p0 = (blockIdx.x - BB) * FW_PTS + w * (FW_PTS / FPS_W);
        for (int k = 0; k < FW_PTS / FPS_W; ++k) {
            int p = p0 + k;
            float fv = feat[(size_t)p * CFEAT + lane];
            float a0 = 0.f, a1 = 0.f;
            #pragma unroll
            for (int c = 0; c < CFEAT; ++c) {
                float fc = __shfl(fv, c);
                a0 = fmaf(fc, smem[c * OUTC + lane], a0);
                a1 = fmaf(fc, smem[c * OUTC + 64 + lane], a1);
            }
            G[(size_t)p * OUTC + lane]      = a0;
            G[(size_t)p * OUTC + 64 + lane] = a1;
        }
        return;
    }

    // ---------------- FPS path ----------------
    float* s_wmax = smem;                       // [16] floats
    int*   s_win  = (int*)(smem + FPS_W);       // [2] ints (double-buffered)

    const int b = blockIdx.x;
    float px[FPS_PT], py[FPS_PT], pz[FPS_PT], dmin[FPS_PT];
    #pragma unroll
    for (int j = 0; j < FPS_PT; ++j) {
        int idx = t + j * FPS_T;
        const float* p = xyz + ((size_t)b * NN + idx) * 3;
        float km  = (float)key_mask[b * NN + idx];
        float off = km * (((float)idx + 10.0f) * 10.0f);  // exact
        px[j] = p[0] + off;
        py[j] = p[1] + off;
        pz[j] = p[2] + off;
        dmin[j] = 1e10f;
        sxyz[(size_t)b * NN + idx] = make_float4(px[j], py[j], pz[j], 0.f);
    }
    if (t < 2) s_win[t] = 0x7fffffff;
    __syncthreads();

    const float4* sb = sxyz + (size_t)b * NN;
    int last = 0;
    for (int it = 0; it < MM; ++it) {
        if (t == 0) fps_idx[b * MM + it] = last;
        const float4 qc = sb[last];            // uniform 16B load
        const float qx = qc.x, qy = qc.y, qz = qc.z;

        // distance update + running max (8 instr/pt, no index tracking)
        float m = -1.0f;
        #pragma unroll
        for (int j = 0; j < FPS_PT; ++j) {
            float dx = px[j] - qx;
            float dy = py[j] - qy;
            float dz = pz[j] - qz;
            float d  = dx * dx + dy * dy + dz * dz;
            float dm = fminf(dmin[j], d);
            dmin[j]  = dm;
            m = fmaxf(m, dm);
        }

        // f32 wave butterfly max
        float wm = m;
        #pragma unroll
        for (int s = 1; s < 64; s <<= 1) wm = fmaxf(wm, __shfl_xor(wm, s));
        if (lane == 0) s_wmax[w] = wm;
        __syncthreads();                                  // B1

        // block max: 4 uniform float4 reads + fmax tree
        float4 v0 = *(const float4*)&s_wmax[0];
        float4 v1 = *(const float4*)&s_wmax[4];
        float4 v2 = *(const float4*)&s_wmax[8];
        float4 v3 = *(const float4*)&s_wmax[12];
        float bmax = fmaxf(
            fmaxf(fmaxf(fmaxf(v0.x, v0.y), fmaxf(v0.z, v0.w)),
                  fmaxf(fmaxf(v1.x, v1.y), fmaxf(v1.z, v1.w))),
            fmaxf(fmaxf(fmaxf(v2.x, v2.y), fmaxf(v2.z, v2.w)),
                  fmaxf(fmaxf(v3.x, v3.y), fmaxf(v3.z, v3.w))));

        if (t == 0) s_win[(it + 1) & 1] = 0x7fffffff;     // reset other slot

        if (m == bmax) {            // rare: winning thread(s) only
            int cand = 0x7fffffff;
            #pragma unroll
            for (int j = FPS_PT - 1; j >= 0; --j)         // descending -> lowest j
                if (dmin[j] == bmax) cand = t + j * FPS_T;
            atomicMin(&s_win[it & 1], cand);              // lowest global index
        }
        __syncthreads();                                  // B2
        last = s_win[it & 1];
    }
}

// ---------------------------------------------------------------------------
// K3: fused ball query + gather + (G + gxyz*Wxyz + b) + LeakyReLU + pool.
// ---------------------------------------------------------------------------
__global__ __launch_bounds__(256) void group_kernel(
    const float* __restrict__ xyz, const int* __restrict__ mask,
    const int* __restrict__ key_mask, const float* __restrict__ W,
    const float* __restrict__ bias, const int* __restrict__ fps_idx,
    const float* __restrict__ G, float* __restrict__ out)
{
    __shared__ int s_idx[4][NS];
    const int t = threadIdx.x, lane = t & 63, w = t >> 6;
    const int q = blockIdx.x * 4 + w;         // 0..16383
    const int b = q >> 11;
    const int gi = fps_idx[q];

    const float* xb = xyz + (size_t)b * NN * 3;
    const float* qp = xb + (size_t)gi * 3;
    const float qx = qp[0], qy = qp[1], qz = qp[2];

    float* out0 = out;
    float* onx  = out  + (size_t)BB * MM * OUTC;
    float* onm  = onx  + (size_t)BB * MM * 3;
    float* onk  = onm  + (size_t)BB * MM;
    if (lane == 0) {
        onx[(size_t)q * 3 + 0] = qx;
        onx[(size_t)q * 3 + 1] = qy;
        onx[(size_t)q * 3 + 2] = qz;
        onm[q] = (float)mask[b * NN + gi];
        onk[q] = (float)key_mask[b * NN + gi];
    }

    const float q2 = qx * qx + qy * qy + qz * qz;
    int have = 0, idx0 = -1;
    for (int base = 0; base < NN; base += 64) {
        int n = base + lane;
        const float* p = xb + n * 3;
        float x = p[0], y = p[1], z = p[2];
        float p2 = x * x + y * y + z * z;
        float dt = qx * x + qy * y + qz * z;
        float d2 = (q2 + p2) - 2.0f * dt;
        bool within = d2 < 0.25f;
        unsigned long long bm = __ballot(within);
        if (bm) {
            if (idx0 < 0) idx0 = base + (__ffsll(bm) - 1);
            if (within) {
                int pos = have + __popcll(bm & ((1ull << lane) - 1ull));
                if (pos < NS) s_idx[w][pos] = n;
            }
            have += (int)__popcll(bm);
            if (have >= NS) break;
        }
    }
    if (have > NS) have = NS;
    if (lane >= have && lane < NS) s_idx[w][lane] = idx0;   // pad with first valid
    __asm__ volatile("s_waitcnt lgkmcnt(0)" ::: "memory");  // LDS writes visible

    const float w0x = W[lane * 67 + 64], w0y = W[lane * 67 + 65], w0z = W[lane * 67 + 66];
    const float w1x = W[(lane + 64) * 67 + 64], w1y = W[(lane + 64) * 67 + 65], w1z = W[(lane + 64) * 67 + 66];
    const float b0 = bias[lane], b1 = bias[lane + 64];
    const float* Gb = G + (size_t)b * NN * OUTC;

    float acc = 0.f, mx = -3.4e38f;
    #pragma unroll 4
    for (int s = 0; s < NS; ++s) {
        int id = s_idx[w][s];
        const float* pr = xb + (size_t)id * 3;
        float dx = pr[0] - qx, dy = pr[1] - qy, dz = pr[2] - qz;
        const float* g = Gb + (size_t)id * OUTC;
        float y0 = g[lane]      + dx * w0x + dy * w0y + dz * w0z + b0;
        float y1 = g[lane + 64] + dx * w1x + dy * w1y + dz * w1z + b1;
        y0 = y0 > 0.f ? y0 : 0.01f * y0;
        y1 = y1 > 0.f ? y1 : 0.01f * y1;
        acc += y0;
        mx = fmaxf(mx, y1);
    }
    out0[(size_t)q * OUTC + lane]      = acc * (1.0f / 32.0f);
    out0[(size_t)q * OUTC + 64 + lane] = mx;
}

// ---------------------------------------------------------------------------
extern "C" void kernel_launch(void* const* d_in, const int* in_sizes, int n_in,
                              void* d_out, int out_size, void* d_ws, size_t ws_size,
                              hipStream_t stream)
{
    const float* feat  = (const float*)d_in[0];
    const float* xyz   = (const float*)d_in[1];
    const int*   mask  = (const int*)d_in[2];
    const int*   kmask = (const int*)d_in[3];
    const float* W     = (const float*)d_in[4];
    const float* bias  = (const float*)d_in[5];
    float* out = (float*)d_out;

    int*    fps_idx = (int*)d_ws;                          // 64 KB
    float*  G       = (float*)((char*)d_ws + 65536);       // 32 MB
    float4* sxyz    = (float4*)((char*)d_ws + 65536 + (size_t)BB * NN * OUTC * 4); // 512 KB

    hipLaunchKernelGGL(fps_featw_kernel, dim3(BB + FW_BLOCKS), dim3(FPS_T), 0, stream,
                       xyz, kmask, feat, W, fps_idx, sxyz, G);
    hipLaunchKernelGGL(group_kernel, dim3(4096), dim3(256), 0, stream,
                       xyz, mask, kmask, W, bias, fps_idx, G, out);
}

// Round 5
// 1892.358 us; speedup vs baseline: 1.5575x; 1.3365x over previous
//
#include <hip/hip_runtime.h>

// Problem constants (fixed by the reference)
#define BB    8
#define NN    8192
#define MM    2048
#define CFEAT 64
#define OUTC  128
#define NS    32
#define NBUCK 128     // buckets per batch
#define BSZ   64      // points per bucket

// ---------------------------------------------------------------------------
// DPP wave64 reductions (canonical GCN scan: row_shr 1/2/4/8, bcast15, bcast31;
// lane 63 holds the full reduction; readlane -> uniform scalar).
// old = self + bound_ctrl=false => invalid/masked lanes are identity.
// ---------------------------------------------------------------------------
template<int C, int R>
__device__ __forceinline__ float dpp_maxf(float v) {
    int t = __builtin_amdgcn_update_dpp(__float_as_int(v), __float_as_int(v), C, R, 0xf, false);
    return fmaxf(v, __int_as_float(t));
}
template<int C, int R>
__device__ __forceinline__ float dpp_minf(float v) {
    int t = __builtin_amdgcn_update_dpp(__float_as_int(v), __float_as_int(v), C, R, 0xf, false);
    return fminf(v, __int_as_float(t));
}
template<int C, int R>
__device__ __forceinline__ unsigned dpp_minu(unsigned v) {
    unsigned t = (unsigned)__builtin_amdgcn_update_dpp((int)v, (int)v, C, R, 0xf, false);
    return v < t ? v : t;
}
__device__ __forceinline__ float wred_maxf(float v) {
    v = dpp_maxf<0x111,0xf>(v); v = dpp_maxf<0x112,0xf>(v);
    v = dpp_maxf<0x114,0xf>(v); v = dpp_maxf<0x118,0xf>(v);
    v = dpp_maxf<0x142,0xa>(v); v = dpp_maxf<0x143,0xc>(v);
    return __int_as_float(__builtin_amdgcn_readlane(__float_as_int(v), 63));
}
__device__ __forceinline__ float wred_minf(float v) {
    v = dpp_minf<0x111,0xf>(v); v = dpp_minf<0x112,0xf>(v);
    v = dpp_minf<0x114,0xf>(v); v = dpp_minf<0x118,0xf>(v);
    v = dpp_minf<0x142,0xa>(v); v = dpp_minf<0x143,0xc>(v);
    return __int_as_float(__builtin_amdgcn_readlane(__float_as_int(v), 63));
}
__device__ __forceinline__ unsigned wred_minu(unsigned v) {
    v = dpp_minu<0x111,0xf>(v); v = dpp_minu<0x112,0xf>(v);
    v = dpp_minu<0x114,0xf>(v); v = dpp_minu<0x118,0xf>(v);
    v = dpp_minu<0x142,0xa>(v); v = dpp_minu<0x143,0xc>(v);
    return (unsigned)__builtin_amdgcn_readlane((int)v, 63);
}

// identical fma shape for point distance and bbox lower bound => lb2 <= d2
// holds in f32 by per-op monotonicity (safe exact skipping).
__device__ __forceinline__ float distsq(float dx, float dy, float dz) {
    return fmaf(dz, dz, fmaf(dy, dy, dx * dx));
}

// ---------------------------------------------------------------------------
// Fused kernel, 64-thread blocks, 148KB dynamic LDS:
//   blocks 0..7    : bucketed FPS, one wave per batch, zero barriers
//   blocks 8..263  : feat*W precompute (G), 256 points each, concurrent
// LDS budget (FPS path):
//   sx,sy,sz,sdmin : 4*8192*4 = 131072
//   bbox (6 arrays): 6* 128*4 =   3072
//   bdmax          :    128*4 =    512
//   bpack          :    128*4 =    512
//   sorig          :   8192*2 =  16384
//   total                     = 151552   (fits 160KB/CU; 1 block/CU)
// ---------------------------------------------------------------------------
#define FPS_LDS_BYTES 151552

__global__ void fps_featw_kernel(
    const float* __restrict__ xyz, const int* __restrict__ key_mask,
    const float* __restrict__ feat, const float* __restrict__ W,
    int* __restrict__ fps_idx, float* __restrict__ G)
{
    extern __shared__ float sm[];
    const int lane = threadIdx.x;   // 0..63

    if (blockIdx.x >= BB) {
        // ---------------- featW path: G[p][o] = feat[p][:64] . W[o][:64] -----
        float* Wt = sm;   // [c][o], 32 KB
        for (int i = lane; i < CFEAT * OUTC; i += 64) {
            int c = i >> 7, o = i & 127;
            Wt[i] = W[o * 67 + c];
        }
        __syncthreads();
        const int p0 = (blockIdx.x - BB) * 256;
        for (int k = 0; k < 256; k += 2) {
            int pA = p0 + k, pB = pA + 1;
            float fa = feat[(size_t)pA * CFEAT + lane];
            float fb = feat[(size_t)pB * CFEAT + lane];
            float a0 = 0.f, a1 = 0.f, b0 = 0.f, b1 = 0.f;
            #pragma unroll 8
            for (int c = 0; c < CFEAT; ++c) {
                float ca = __shfl(fa, c), cb = __shfl(fb, c);
                float w0 = Wt[c * OUTC + lane], w1 = Wt[c * OUTC + 64 + lane];
                a0 = fmaf(ca, w0, a0); a1 = fmaf(ca, w1, a1);
                b0 = fmaf(cb, w0, b0); b1 = fmaf(cb, w1, b1);
            }
            G[(size_t)pA * OUTC + lane]      = a0;
            G[(size_t)pA * OUTC + 64 + lane] = a1;
            G[(size_t)pB * OUTC + lane]      = b0;
            G[(size_t)pB * OUTC + 64 + lane] = b1;
        }
        return;
    }

    // ---------------- FPS path ----------------
    float*          sx    = sm;                       // [8192]
    float*          sy    = sx + NN;
    float*          sz    = sy + NN;
    float*          sdmin = sz + NN;
    float*          blox  = sdmin + NN;               // [128] x6 bbox
    float*          bloy  = blox + NBUCK;
    float*          bloz  = bloy + NBUCK;
    float*          bhix  = bloz + NBUCK;
    float*          bhiy  = bhix + NBUCK;
    float*          bhiz  = bhiy + NBUCK;
    float*          bdmax = bhiz + NBUCK;             // [128] sticky max dmin
    unsigned*       bpack = (unsigned*)(bdmax + NBUCK); // [128] (orig<<13)|pos
    unsigned short* sorig = (unsigned short*)(bpack + NBUCK); // [8192]

    const int b = blockIdx.x;

    // pass A: count masked points
    int nm_total = 0;
    for (int c = 0; c < 128; ++c) {
        int km = key_mask[b * NN + c * 64 + lane];
        nm_total += (int)__popcll(__ballot(km != 0));
    }
    const int NU = NN - nm_total;   // masked points go to positions [NU, NN)

    // pass B: stable partition (unmasked by idx, then masked by idx) + scale
    int nu_seen = 0, nm_seen = 0;
    for (int c = 0; c < 128; ++c) {
        int orig = c * 64 + lane;
        const float* p = xyz + ((size_t)b * NN + orig) * 3;
        float x = p[0], y = p[1], z = p[2];
        int km = key_mask[b * NN + orig];
        float off = km ? ((float)orig + 10.0f) * 10.0f : 0.0f;  // exact
        unsigned long long bm = __ballot(km != 0);
        int below = (int)__popcll(bm & ((1ull << lane) - 1ull));
        int pos = km ? (NU + nm_seen + below) : (nu_seen + (lane - below));
        sx[pos] = x + off; sy[pos] = y + off; sz[pos] = z + off;
        sdmin[pos] = 1e10f;
        sorig[pos] = (unsigned short)orig;
        int cm = (int)__popcll(bm);
        nm_seen += cm; nu_seen += 64 - cm;
    }

    // pass C: per-bucket bbox + init keys
    for (int j = 0; j < NBUCK; ++j) {
        int p = (j << 6) + lane;
        float x = sx[p], y = sy[p], z = sz[p];
        float lox = wred_minf(x), hix = wred_maxf(x);
        float loy = wred_minf(y), hiy = wred_maxf(y);
        float loz = wred_minf(z), hiz = wred_maxf(z);
        unsigned pk = ((unsigned)sorig[p] << 13) | (unsigned)p;
        unsigned mn = wred_minu(pk);
        if (lane == 0) {
            blox[j] = lox; bhix[j] = hix;
            bloy[j] = loy; bhiy[j] = hiy;
            bloz[j] = loz; bhiz[j] = hiz;
            bdmax[j] = 1e10f; bpack[j] = mn;
        }
    }

    // main loop: 2048 selections, zero barriers (single wave)
    int km0 = key_mask[b * NN];
    int pos0 = km0 ? NU : 0;                 // position of orig index 0
    float qx = sx[pos0], qy = sy[pos0], qz = sz[pos0];
    int s_last = 0;

    for (int it = 0; it < MM; ++it) {
        if (lane == 0) fps_idx[b * MM + it] = s_last;

        // phase 1: skip tests (2 buckets per lane)
        const int j0 = lane, j1 = lane + 64;
        float dx0 = fmaxf(fmaxf(blox[j0] - qx, qx - bhix[j0]), 0.f);
        float dy0 = fmaxf(fmaxf(bloy[j0] - qy, qy - bhiy[j0]), 0.f);
        float dz0 = fmaxf(fmaxf(bloz[j0] - qz, qz - bhiz[j0]), 0.f);
        float lb0 = distsq(dx0, dy0, dz0);
        float dx1 = fmaxf(fmaxf(blox[j1] - qx, qx - bhix[j1]), 0.f);
        float dy1 = fmaxf(fmaxf(bloy[j1] - qy, qy - bhiy[j1]), 0.f);
        float dz1 = fmaxf(fmaxf(bloz[j1] - qz, qz - bhiz[j1]), 0.f);
        float lb1 = distsq(dx1, dy1, dz1);
        unsigned long long m0 = __ballot(lb0 < bdmax[j0]);
        unsigned long long m1 = __ballot(lb1 < bdmax[j1]);

        // phase 2: update needed buckets (cooperative, 1 point/lane)
        while (m0 | m1) {
            int j;
            if (m0) { j = __ffsll(m0) - 1;        m0 &= m0 - 1; }
            else    { j = (__ffsll(m1) - 1) + 64; m1 &= m1 - 1; }
            int p = (j << 6) + lane;
            float dx = sx[p] - qx, dy = sy[p] - qy, dz = sz[p] - qz;
            float d  = distsq(dx, dy, dz);
            float dmn = fminf(sdmin[p], d);
            sdmin[p] = dmn;
            float dmax = wred_maxf(dmn);
            unsigned pk = (dmn == dmax)
                        ? (((unsigned)sorig[p] << 13) | (unsigned)p)
                        : 0xffffffffu;
            unsigned mn = wred_minu(pk);
            if (lane == 0) { bdmax[j] = dmax; bpack[j] = mn; }
        }

        // phase 3: global argmax over 128 sticky bucket keys
        float d0 = bdmax[j0], d1 = bdmax[j1];
        float bmax = wred_maxf(fmaxf(d0, d1));
        unsigned c0 = (d0 == bmax) ? bpack[j0] : 0xffffffffu;
        unsigned c1 = (d1 == bmax) ? bpack[j1] : 0xffffffffu;
        unsigned win = wred_minu(c0 < c1 ? c0 : c1);
        s_last = (int)(win >> 13);
        int pos = (int)(win & 8191u);
        qx = sx[pos]; qy = sy[pos]; qz = sz[pos];
    }
}

// ---------------------------------------------------------------------------
// K3: fused ball query + gather + (G + gxyz*Wxyz + b) + LeakyReLU + pool.
// ---------------------------------------------------------------------------
__global__ __launch_bounds__(256) void group_kernel(
    const float* __restrict__ xyz, const int* __restrict__ mask,
    const int* __restrict__ key_mask, const float* __restrict__ W,
    const float* __restrict__ bias, const int* __restrict__ fps_idx,
    const float* __restrict__ G, float* __restrict__ out)
{
    __shared__ int s_idx[4][NS];
    const int t = threadIdx.x, lane = t & 63, w = t >> 6;
    const int q = blockIdx.x * 4 + w;         // 0..16383
    const int b = q >> 11;
    const int gi = fps_idx[q];

    const float* xb = xyz + (size_t)b * NN * 3;
    const float* qp = xb + (size_t)gi * 3;
    const float qx = qp[0], qy = qp[1], qz = qp[2];

    float* out0 = out;
    float* onx  = out  + (size_t)BB * MM * OUTC;
    float* onm  = onx  + (size_t)BB * MM * 3;
    float* onk  = onm  + (size_t)BB * MM;
    if (lane == 0) {
        onx[(size_t)q * 3 + 0] = qx;
        onx[(size_t)q * 3 + 1] = qy;
        onx[(size_t)q * 3 + 2] = qz;
        onm[q] = (float)mask[b * NN + gi];
        onk[q] = (float)key_mask[b * NN + gi];
    }

    const float q2 = qx * qx + qy * qy + qz * qz;
    int have = 0, idx0 = -1;
    for (int base = 0; base < NN; base += 64) {
        int n = base + lane;
        const float* p = xb + n * 3;
        float x = p[0], y = p[1], z = p[2];
        float p2 = x * x + y * y + z * z;
        float dt = qx * x + qy * y + qz * z;
        float d2 = (q2 + p2) - 2.0f * dt;
        bool within = d2 < 0.25f;
        unsigned long long bm = __ballot(within);
        if (bm) {
            if (idx0 < 0) idx0 = base + (__ffsll(bm) - 1);
            if (within) {
                int pos = have + __popcll(bm & ((1ull << lane) - 1ull));
                if (pos < NS) s_idx[w][pos] = n;
            }
            have += (int)__popcll(bm);
            if (have >= NS) break;
        }
    }
    if (have > NS) have = NS;
    if (lane >= have && lane < NS) s_idx[w][lane] = idx0;   // pad with first valid
    __asm__ volatile("s_waitcnt lgkmcnt(0)" ::: "memory");  // LDS writes visible

    const float w0x = W[lane * 67 + 64], w0y = W[lane * 67 + 65], w0z = W[lane * 67 + 66];
    const float w1x = W[(lane + 64) * 67 + 64], w1y = W[(lane + 64) * 67 + 65], w1z = W[(lane + 64) * 67 + 66];
    const float b0 = bias[lane], b1 = bias[lane + 64];
    const float* Gb = G + (size_t)b * NN * OUTC;

    float acc = 0.f, mx = -3.4e38f;
    #pragma unroll 4
    for (int s = 0; s < NS; ++s) {
        int id = s_idx[w][s];
        const float* pr = xb + (size_t)id * 3;
        float dx = pr[0] - qx, dy = pr[1] - qy, dz = pr[2] - qz;
        const float* g = Gb + (size_t)id * OUTC;
        float y0 = g[lane]      + dx * w0x + dy * w0y + dz * w0z + b0;
        float y1 = g[lane + 64] + dx * w1x + dy * w1y + dz * w1z + b1;
        y0 = y0 > 0.f ? y0 : 0.01f * y0;
        y1 = y1 > 0.f ? y1 : 0.01f * y1;
        acc += y0;
        mx = fmaxf(mx, y1);
    }
    out0[(size_t)q * OUTC + lane]      = acc * (1.0f / 32.0f);
    out0[(size_t)q * OUTC + 64 + lane] = mx;
}

// ---------------------------------------------------------------------------
extern "C" void kernel_launch(void* const* d_in, const int* in_sizes, int n_in,
                              void* d_out, int out_size, void* d_ws, size_t ws_size,
                              hipStream_t stream)
{
    const float* feat  = (const float*)d_in[0];
    const float* xyz   = (const float*)d_in[1];
    const int*   mask  = (const int*)d_in[2];
    const int*   kmask = (const int*)d_in[3];
    const float* W     = (const float*)d_in[4];
    const float* bias  = (const float*)d_in[5];
    float* out = (float*)d_out;

    int*   fps_idx = (int*)d_ws;                          // 64 KB
    float* G       = (float*)((char*)d_ws + 65536);       // 32 MB

    // opt-in to >64KB dynamic LDS (host-side setting; graph-capture safe)
    hipFuncSetAttribute((const void*)fps_featw_kernel,
                        hipFuncAttributeMaxDynamicSharedMemorySize, FPS_LDS_BYTES);

    hipLaunchKernelGGL(fps_featw_kernel, dim3(BB + 256), dim3(64), FPS_LDS_BYTES, stream,
                       xyz, kmask, feat, W, fps_idx, G);
    hipLaunchKernelGGL(group_kernel, dim3(4096), dim3(256), 0, stream,
                       xyz, mask, kmask, W, bias, fps_idx, G, out);
}